// Round 16
// baseline (185.556 us; speedup 1.0000x reference)
//
#include <hip/hip_runtime.h>
#include <hip/hip_bf16.h>

#define BROWS 32768
#define CDIM 1000
#define CPAD 1024
#define HDIM 128
// Bijective LDS word swizzle (proven v6): XOR bits5-7 into bits2-4; keeps 4-word
// chunks contiguous (b128) and balances the 64B-lane-stride pattern across banks.
#define SWZ(w) ((w) ^ ((((w) >> 5) & 7) << 2))

typedef __attribute__((ext_vector_type(8))) short short8;
typedef __attribute__((ext_vector_type(4))) float f32x4;

__device__ inline unsigned short f2bf(float x) {
    unsigned int b = __float_as_uint(x);
    unsigned int r = (b + 0x7FFFu + ((b >> 16) & 1u)) >> 16;  // RNE
    return (unsigned short)r;
}
__device__ inline float bf2f(unsigned short u) {
    return __uint_as_float(((unsigned int)u) << 16);
}

// ---------------- prep: transpose weights to [N][K] bf16, zero-padded ----------------
__global__ __launch_bounds__(256) void k_prep(const float* __restrict__ W1,
                                              const float* __restrict__ W2,
                                              const float* __restrict__ W3,
                                              unsigned short* __restrict__ W1t,
                                              unsigned short* __restrict__ W2t,
                                              unsigned short* __restrict__ W3t) {
    const int idx = blockIdx.x * 256 + threadIdx.x;  // [0, 131072)
    {   // W1t[n][k], n<128, k<1024 ; W1 is [1000][128]
        const int n = idx >> 10, k = idx & 1023;
        W1t[idx] = (k < CDIM) ? f2bf(W1[(size_t)k * HDIM + n]) : (unsigned short)0;
    }
    {   // W3t[n][k], n<1024, k<128 ; W3 is [128][1000]
        const int n = idx >> 7, k = idx & 127;
        W3t[idx] = (n < CDIM) ? f2bf(W3[(size_t)k * CDIM + n]) : (unsigned short)0;
    }
    if (idx < 16384) {  // W2t[n][k], 128x128 ; W2 is [128][128]
        const int n = idx >> 7, k = idx & 127;
        W2t[idx] = f2bf(W2[(size_t)k * HDIM + n]);
    }
}

// ---------------- softmax: one wave per row, bf16 prob (padded 1024) + rstat ---------
__global__ __launch_bounds__(256) void k_softmax(const float* __restrict__ logits,
                                                 unsigned short* __restrict__ prob,
                                                 float2* __restrict__ rstat) {
    const int wv = threadIdx.x >> 6, lane = threadIdx.x & 63;
    const int row = (blockIdx.x << 2) + wv;
    const int base = lane << 4;
    const float* lrow = logits + (size_t)row * CDIM;
    float lg[16];
#pragma unroll
    for (int q = 0; q < 4; ++q) {
        const int c = base + (q << 2);
        if (c < CDIM) {
            const float4 v4 = *reinterpret_cast<const float4*>(lrow + c);
            lg[q * 4] = v4.x; lg[q * 4 + 1] = v4.y; lg[q * 4 + 2] = v4.z; lg[q * 4 + 3] = v4.w;
        } else {
            lg[q * 4] = lg[q * 4 + 1] = lg[q * 4 + 2] = lg[q * 4 + 3] = -INFINITY;
        }
    }
    float mx = lg[0];
#pragma unroll
    for (int e = 1; e < 16; ++e) mx = fmaxf(mx, lg[e]);
#pragma unroll
    for (int off = 32; off >= 1; off >>= 1) mx = fmaxf(mx, __shfl_xor(mx, off));
    float p[16], s = 0.f;
#pragma unroll
    for (int e = 0; e < 16; ++e) { p[e] = __expf(lg[e] - mx); s += p[e]; }
#pragma unroll
    for (int off = 32; off >= 1; off >>= 1) s += __shfl_xor(s, off);
    const float inv = 1.f / s;
    unsigned int w[8];
#pragma unroll
    for (int i = 0; i < 8; ++i) {
        const unsigned int lo = f2bf(p[2 * i] * inv);
        const unsigned int hi = f2bf(p[2 * i + 1] * inv);
        w[i] = lo | (hi << 16);
    }
    uint4 o0, o1;
    o0.x = w[0]; o0.y = w[1]; o0.z = w[2]; o0.w = w[3];
    o1.x = w[4]; o1.y = w[5]; o1.z = w[6]; o1.w = w[7];
    uint4* dst = reinterpret_cast<uint4*>(prob + (size_t)row * CPAD + base);
    dst[0] = o0; dst[1] = o1;
    if (lane == 0) rstat[row] = make_float2(mx, inv);   // bitwise-same stats for sortfinish
}

// ---------------- GEMM: C[M,N] = epi(A[M,K] @ Bt[N,K]^T + bias) ----------------------
// 512 threads = 8 waves (4m x 2n), block tile 128x128, BK=64, XOR-swizzled LDS chunks.
// EPI 0: relu(v + bias). EPI 1: sigmoid except col nlimit-1 raw; stores n < nlimit.
// In-place outp==A is safe per-128-row-block (barrier orders reads before writes).
template <int EPI>
__global__ __launch_bounds__(512) void k_gemm(const unsigned short* __restrict__ A, int lda,
                                              const unsigned short* __restrict__ Bt, int ldb,
                                              const float* __restrict__ bias,
                                              unsigned short* __restrict__ outp, int ldo,
                                              int K, int nlimit) {
    __shared__ uint4 As[128 * 8];
    __shared__ uint4 Bs[128 * 8];
    const int tid = threadIdx.x;
    const int bm = blockIdx.x, bn = blockIdx.y;
    const int lane = tid & 63, w = tid >> 6;
    const int wm = (w >> 1) << 5;
    const int wn = (w & 1) << 6;
    const int l15 = lane & 15, l4 = lane >> 4;
    f32x4 acc[2][4] = {};

    for (int k0 = 0; k0 < K; k0 += 64) {
        __syncthreads();
#pragma unroll
        for (int i = 0; i < 2; ++i) {
            const int cid = tid + (i << 9);
            const int r = cid >> 3, c = cid & 7;
            As[(r << 3) + (c ^ (r & 7))] =
                *reinterpret_cast<const uint4*>(A + (size_t)(bm * 128 + r) * lda + k0 + (c << 3));
            Bs[(r << 3) + (c ^ (r & 7))] =
                *reinterpret_cast<const uint4*>(Bt + (size_t)(bn * 128 + r) * ldb + k0 + (c << 3));
        }
        __syncthreads();
#pragma unroll
        for (int kk = 0; kk < 2; ++kk) {
            short8 a[2], b[4];
#pragma unroll
            for (int mf = 0; mf < 2; ++mf) {
                const int r = wm + (mf << 4) + l15;
                a[mf] = *reinterpret_cast<const short8*>(&As[(r << 3) + (((kk << 2) + l4) ^ (r & 7))]);
            }
#pragma unroll
            for (int nf = 0; nf < 4; ++nf) {
                const int r = wn + (nf << 4) + l15;
                b[nf] = *reinterpret_cast<const short8*>(&Bs[(r << 3) + (((kk << 2) + l4) ^ (r & 7))]);
            }
#pragma unroll
            for (int mf = 0; mf < 2; ++mf)
#pragma unroll
                for (int nf = 0; nf < 4; ++nf)
                    acc[mf][nf] = __builtin_amdgcn_mfma_f32_16x16x32_bf16(a[mf], b[nf], acc[mf][nf], 0, 0, 0);
        }
    }
#pragma unroll
    for (int mf = 0; mf < 2; ++mf) {
#pragma unroll
        for (int nf = 0; nf < 4; ++nf) {
            const int n = (bn << 7) + wn + (nf << 4) + l15;
            if (EPI == 1 && n >= nlimit) continue;   // compact output: skip pad cols
            const float bv = bias[n];
#pragma unroll
            for (int r = 0; r < 4; ++r) {
                const int m = (bm << 7) + wm + (mf << 4) + (l4 << 2) + r;
                float v = acc[mf][nf][r] + bv;
                if (EPI == 0) {
                    v = fmaxf(v, 0.f);
                } else {
                    if (n != nlimit - 1) v = 1.f / (1.f + __expf(-v));
                }
                outp[(size_t)m * ldo + n] = f2bf(v);
            }
        }
    }
}

// ---------------- sort + finish v8: 2 independent rows per wave (ILP) ----------------
// Theory (r15): the per-row cost is a ~6-deep dependent-LDS-round-trip chain that low
// occupancy can't hide. Two rows per wave = two independent chains in one instruction
// stream; the compiler interleaves them so one chain's LDS latency covers the other's
// issue. Separate 1024-word LDS regions per row; conflicts are per-instruction so the
// interleave adds none. swk recomputed from p (saves 32 VGPR vs storing).
__global__ __launch_bounds__(256) void k_sortfinish(const float* __restrict__ logits,
                                                    const float2* __restrict__ rstat,
                                                    const unsigned short* __restrict__ cal,
                                                    float* __restrict__ out) {
    __shared__ unsigned int shm[8 * 1024];   // 4 waves x 2 regions x 1024 words = 32KB
    const int wv = threadIdx.x >> 6, lane = threadIdx.x & 63;
    const int base = lane << 4;
    const int row0 = (blockIdx.x << 3) + (wv << 1);   // wave owns rows row0, row0+1
    unsigned int* const smx[2] = { &shm[wv << 11], &shm[(wv << 11) + 1024] };

    int cb[4];
#pragma unroll
    for (int j = 0; j < 4; ++j) cb[j] = SWZ(base + (j << 2));

    // ---- load both rows' inputs ----
    float lg[2][16]; unsigned int cw[2][8]; float mxv[2], invv[2];
#pragma unroll
    for (int h = 0; h < 2; ++h) {
        const int row = row0 + h;
        const float* lrow = logits + (size_t)row * CDIM;
#pragma unroll
        for (int q = 0; q < 4; ++q) {
            const int c = base + (q << 2);
            if (c < CDIM) {
                const float4 v4 = *reinterpret_cast<const float4*>(lrow + c);
                lg[h][q * 4] = v4.x; lg[h][q * 4 + 1] = v4.y;
                lg[h][q * 4 + 2] = v4.z; lg[h][q * 4 + 3] = v4.w;
            } else {
                lg[h][q * 4] = lg[h][q * 4 + 1] = lg[h][q * 4 + 2] = lg[h][q * 4 + 3] = -INFINITY;
            }
        }
        const unsigned short* crow = cal + (size_t)row * CDIM + base;   // overread >=1000: in-ws
        const uint4 c0 = *reinterpret_cast<const uint4*>(crow);
        const uint4 c1 = *reinterpret_cast<const uint4*>(crow + 8);
        cw[h][0] = c0.x; cw[h][1] = c0.y; cw[h][2] = c0.z; cw[h][3] = c0.w;
        cw[h][4] = c1.x; cw[h][5] = c1.y; cw[h][6] = c1.z; cw[h][7] = c1.w;
        const float2 st = rstat[row];
        mxv[h] = st.x; invv[h] = st.y;
    }

    // ---- zero histograms (both regions) ----
    {
        uint4 z; z.x = 0; z.y = 0; z.z = 0; z.w = 0;
#pragma unroll
        for (int h = 0; h < 2; ++h)
#pragma unroll
            for (int j = 0; j < 4; ++j) *reinterpret_cast<uint4*>(&smx[h][cb[j]]) = z;
    }

    // ---- probs ----
    float p[2][16];
#pragma unroll
    for (int h = 0; h < 2; ++h)
#pragma unroll
        for (int e = 0; e < 16; ++e) p[h][e] = __expf(lg[h][e] - mxv[h]) * invv[h];

    // ---- single atomic pass per row: histogram + stable in-bucket offset ----
    unsigned int offv[2][16];
#pragma unroll
    for (int h = 0; h < 2; ++h)
#pragma unroll
        for (int e = 0; e < 16; ++e) {
            const unsigned int key = __float_as_uint(p[h][e]) >> 20;  // 11-bit, <=1016
            offv[h][e] = (base + e < CDIM) ? atomicAdd(&smx[h][SWZ((int)key)], 1u) : 0u;
        }

    // ---- bucket suffix-scans (independent per row; compiler interleaves) ----
#pragma unroll
    for (int h = 0; h < 2; ++h) {
        unsigned int c16[16];
#pragma unroll
        for (int j = 0; j < 4; ++j) {
            const uint4 v4 = *reinterpret_cast<const uint4*>(&smx[h][cb[j]]);
            c16[4 * j] = v4.x; c16[4 * j + 1] = v4.y; c16[4 * j + 2] = v4.z; c16[4 * j + 3] = v4.w;
        }
        unsigned int lsum = 0;
#pragma unroll
        for (int e = 0; e < 16; ++e) lsum += c16[e];
        unsigned int suf = lsum;
#pragma unroll
        for (int off = 1; off < 64; off <<= 1) {
            const unsigned int u = __shfl_down(suf, off);
            if (lane + off < 64) suf += u;
        }
        unsigned int run = suf - lsum;
        unsigned int stv[16];
#pragma unroll
        for (int e = 15; e >= 0; --e) { stv[e] = run; run += c16[e]; }
#pragma unroll
        for (int j = 0; j < 4; ++j) {
            uint4 v4;
            v4.x = stv[4 * j]; v4.y = stv[4 * j + 1]; v4.z = stv[4 * j + 2]; v4.w = stv[4 * j + 3];
            *reinterpret_cast<uint4*>(&smx[h][cb[j]]) = v4;
        }
    }

    // ---- rank = start[key] + offset (key recomputed from p; saves 32 VGPR) ----
    int swr[2][16];
#pragma unroll
    for (int h = 0; h < 2; ++h)
#pragma unroll
        for (int e = 0; e < 16; ++e) {
            const unsigned int key = __float_as_uint(p[h][e]) >> 20;
            const int rk = (base + e < CDIM) ? (int)(smx[h][SWZ((int)key)] + offv[h][e]) : 1023;
            swr[h][e] = SWZ(rk);
        }

    // ---- scatter probs to rank order ----
#pragma unroll
    for (int h = 0; h < 2; ++h)
#pragma unroll
        for (int e = 0; e < 16; ++e)
            if (base + e < CDIM) smx[h][swr[h][e]] = __float_as_uint(p[h][e]);

    // ---- blocked read of sorted probs ----
    float sp[2][16];
#pragma unroll
    for (int h = 0; h < 2; ++h)
#pragma unroll
        for (int j = 0; j < 4; ++j) {
            const uint4 v4 = *reinterpret_cast<const uint4*>(&smx[h][cb[j]]);
            sp[h][4 * j] = __uint_as_float(v4.x); sp[h][4 * j + 1] = __uint_as_float(v4.y);
            sp[h][4 * j + 2] = __uint_as_float(v4.z); sp[h][4 * j + 3] = __uint_as_float(v4.w);
        }

    // ---- diffs * cal, suffix sums (independent chains) ----
    float lsuf[2][16], after[2];
#pragma unroll
    for (int h = 0; h < 2; ++h) {
        const float spn_next = __shfl_down(sp[h][0], 1);
        float v[16];
#pragma unroll
        for (int e = 0; e < 16; ++e) {
            const int r = base + e;
            const float cv = bf2f((unsigned short)((cw[h][e >> 1] >> ((e & 1) * 16)) & 0xFFFFu));
            const float spn = (e < 15) ? sp[h][e + 1] : spn_next;
            float val;
            if (r < CDIM - 1) val = (sp[h][e] - spn) * cv;
            else if (r == CDIM - 1) val = cv;
            else val = 0.f;
            v[e] = val;
        }
        float run = 0.f;
#pragma unroll
        for (int e = 15; e >= 0; --e) { run += v[e]; lsuf[h][e] = run; }
        float pi = run;
#pragma unroll
        for (int off = 1; off < 64; off <<= 1) {
            const float u = __shfl_up(pi, off);
            if (lane >= off) pi += u;
        }
        const float tot = __shfl(pi, 63);
        after[h] = tot - pi;
    }

    // ---- S arrays overwrite sorted probs, gather by rank ----
#pragma unroll
    for (int h = 0; h < 2; ++h)
#pragma unroll
        for (int j = 0; j < 4; ++j) {
            uint4 v4;
            v4.x = __float_as_uint(lsuf[h][4 * j] + after[h]);
            v4.y = __float_as_uint(lsuf[h][4 * j + 1] + after[h]);
            v4.z = __float_as_uint(lsuf[h][4 * j + 2] + after[h]);
            v4.w = __float_as_uint(lsuf[h][4 * j + 3] + after[h]);
            *reinterpret_cast<uint4*>(&smx[h][cb[j]]) = v4;
        }
    float f[2][16];
#pragma unroll
    for (int h = 0; h < 2; ++h)
#pragma unroll
        for (int e = 0; e < 16; ++e) f[h][e] = __uint_as_float(smx[h][swr[h][e]]);

    // ---- out = logits + fitted, both rows ----
#pragma unroll
    for (int h = 0; h < 2; ++h)
#pragma unroll
        for (int q = 0; q < 4; ++q) {
            const int c = base + (q << 2);
            if (c < CDIM) {
                float4 o;
                o.x = lg[h][q * 4] + f[h][q * 4];
                o.y = lg[h][q * 4 + 1] + f[h][q * 4 + 1];
                o.z = lg[h][q * 4 + 2] + f[h][q * 4 + 2];
                o.w = lg[h][q * 4 + 3] + f[h][q * 4 + 3];
                *reinterpret_cast<float4*>(out + (size_t)(row0 + h) * CDIM + c) = o;
            }
        }
}

// ---------------- host ----------------
extern "C" void kernel_launch(void* const* d_in, const int* in_sizes, int n_in,
                              void* d_out, int out_size, void* d_ws, size_t ws_size,
                              hipStream_t stream) {
    const float* logits = (const float*)d_in[0];
    const float* W1 = (const float*)d_in[1];
    const float* b1 = (const float*)d_in[2];
    const float* W2 = (const float*)d_in[3];
    const float* b2 = (const float*)d_in[4];
    const float* W3 = (const float*)d_in[5];
    const float* b3 = (const float*)d_in[6];
    float* out = (float*)d_out;

    char* ws = (char*)d_ws;
    unsigned short* prob = (unsigned short*)ws;                 // 64 MB (CPAD stride)
    unsigned short* h12  = (unsigned short*)(ws + 67108864);    // 8 MB: h1, then h2 in-place
    float2*         rstat= (float2*)(ws + 75497472);            // 256 KB
    unsigned short* W1t  = (unsigned short*)(ws + 75759616);    // 256 KB
    unsigned short* W2t  = (unsigned short*)(ws + 76021760);    // 32 KB
    unsigned short* W3t  = (unsigned short*)(ws + 76054528);    // 256 KB -> 76.3 MB total
    unsigned short* cal  = prob;  // prob dead after gemm1; cal compact ldo=CDIM

    k_prep<<<512, 256, 0, stream>>>(W1, W2, W3, W1t, W2t, W3t);
    k_softmax<<<BROWS / 4, 256, 0, stream>>>(logits, prob, rstat);
    k_gemm<0><<<dim3(BROWS / 128, 1), 512, 0, stream>>>(prob, CPAD, W1t, CPAD, b1, h12, HDIM, CPAD, 0);
    k_gemm<0><<<dim3(BROWS / 128, 1), 512, 0, stream>>>(h12, HDIM, W2t, HDIM, b2, h12, HDIM, HDIM, 0);
    k_gemm<1><<<dim3(BROWS / 128, 8), 512, 0, stream>>>(h12, HDIM, W3t, HDIM, b3, cal, CDIM, HDIM, CDIM);
    k_sortfinish<<<BROWS / 8, 256, 0, stream>>>(logits, rstat, cal, out);
}